// Round 4
// baseline (59.988 us; speedup 1.0000x reference)
//
#include <hip/hip_runtime.h>
#include <hip/hip_bf16.h>
#include <math.h>

#define BDIM 4096
#define DDIM 256
#define N2   8192
#define CSPLIT 16
#define BROWS 256            // rows per block (4 waves x 64 rows)
#define CPB (N2 / CSPLIT)    // 512 cols per block
#define BN 32                // col tile (16 KB per buffer)
#define NT (CPB / BN)        // 16 tiles per block
#define RING 5               // LDS ring buffers (must be >= PD+2)
#define PD 3                 // prefetch depth (tiles in flight)
#define TILEB (BN * DDIM * 2)  // 16384 bytes per buffer

typedef __bf16 bf16x8 __attribute__((ext_vector_type(8)));
typedef __bf16 bf16x4 __attribute__((ext_vector_type(4)));
typedef float  f32x4  __attribute__((ext_vector_type(4)));

#define WAITVM(N) asm volatile("s_waitcnt vmcnt(" #N ")" ::: "memory")

__device__ __forceinline__ void gload_lds16(const __bf16* g, void* lds) {
    __builtin_amdgcn_global_load_lds(
        (const __attribute__((address_space(1))) unsigned int*)g,
        (__attribute__((address_space(3))) unsigned int*)lds, 16, 0, 0);
}

// ---------------- Kernel 1: L2-normalize rows, emit bf16 reps + fp32 positive dots ----------------
__global__ __launch_bounds__(256) void norm_kernel(const float* __restrict__ z1,
                                                   const float* __restrict__ z2,
                                                   __bf16* __restrict__ reps,
                                                   float* __restrict__ pos) {
    int gwave = (blockIdx.x * 256 + threadIdx.x) >> 6;
    int lane  = threadIdx.x & 63;
    if (gwave >= BDIM) return;

    const float4 a = *(const float4*)&z1[(size_t)gwave * DDIM + lane * 4];
    const float4 b = *(const float4*)&z2[(size_t)gwave * DDIM + lane * 4];

    float s1 = a.x*a.x + a.y*a.y + a.z*a.z + a.w*a.w;
    float s2 = b.x*b.x + b.y*b.y + b.z*b.z + b.w*b.w;
    float d  = a.x*b.x + a.y*b.y + a.z*b.z + a.w*b.w;
    #pragma unroll
    for (int off = 32; off; off >>= 1) {
        s1 += __shfl_xor(s1, off);
        s2 += __shfl_xor(s2, off);
        d  += __shfl_xor(d,  off);
    }
    float r1 = 1.0f / fmaxf(sqrtf(s1), 1e-12f);
    float r2 = 1.0f / fmaxf(sqrtf(s2), 1e-12f);

    bf16x4 w1, w2;
    w1[0] = (__bf16)(a.x * r1); w1[1] = (__bf16)(a.y * r1);
    w1[2] = (__bf16)(a.z * r1); w1[3] = (__bf16)(a.w * r1);
    w2[0] = (__bf16)(b.x * r2); w2[1] = (__bf16)(b.y * r2);
    w2[2] = (__bf16)(b.z * r2); w2[3] = (__bf16)(b.w * r2);
    *(bf16x4*)&reps[(size_t)gwave * DDIM + lane * 4]          = w1;
    *(bf16x4*)&reps[(size_t)(gwave + BDIM) * DDIM + lane * 4] = w2;

    if (lane == 0) pos[gwave] = d * r1 * r2;
}

// ---------------- Kernel 2: counted-vmcnt pipelined GEMM + exp-sum ----------------
// 512 blocks (32 rowgroups x 16 colslices), 4 waves, 64 rows/wave in registers.
// B streams through a 5-buffer LDS ring via global_load_lds(16B) with XOR-
// swizzled source; prefetch depth 3. Per tile: stage(t+3) -> vmcnt(12) (own
// tile-t loads certified, 12 newer stay in flight ACROSS the barrier) ->
// raw s_barrier (no drain) -> compute. Ring>=PD+2 makes the stage clobber
// only tile t-2's buffer (all waves done with it before the barrier passed).
__global__ __launch_bounds__(256, 2) void lse4_kernel(const __bf16* __restrict__ reps,
                                                      float* __restrict__ partial) {
    __shared__ __attribute__((aligned(16))) __bf16 Bt[RING][BN * DDIM];  // 80 KB

    const int tid  = threadIdx.x;
    const int wave = tid >> 6;
    const int lane = tid & 63;
    const int l15  = lane & 15;
    const int lq   = lane >> 4;
    const int rg   = blockIdx.x >> 4;
    const int cs   = blockIdx.x & 15;
    const int r0   = rg * BROWS;
    const int c0   = cs * CPB;

    // hoist A fragments: 4 groups of 16 rows, full K=256 (lives in VGPR/AGPR)
    bf16x8 afr[4][8];
    #pragma unroll
    for (int g = 0; g < 4; ++g) {
        const __bf16* ap = reps + (size_t)(r0 + wave * 64 + g * 16 + l15) * DDIM + lq * 8;
        #pragma unroll
        for (int ks = 0; ks < 8; ++ks)
            afr[g][ks] = *(const bf16x8*)(ap + ks * 32);
    }

    f32x4 S[4];
    #pragma unroll
    for (int g = 0; g < 4; ++g)
        #pragma unroll
        for (int r = 0; r < 4; ++r) S[g][r] = 0.f;

    // stage tile t into ring buffer buf: linear LDS dest, XOR-swizzled source
    auto stage = [&](int buf, int t) {
        const int gcol = c0 + t * BN;
        #pragma unroll
        for (int i = 0; i < 4; ++i) {
            const int base = wave * 4096 + i * 1024;     // wave-uniform byte offset
            const int L    = base + lane * 16;
            const int c    = L >> 9;                     // tile col 0..31
            const int ch   = (L >> 4) & 31;              // 16B chunk in row
            const __bf16* g = reps + (size_t)(gcol + c) * DDIM + ((ch ^ (c & 7)) << 3);
            gload_lds16(g, (char*)&Bt[0][0] + buf * TILEB + base);
        }
    };

    auto compute = [&](int buf) {
        const char* bufc = (const char*)&Bt[0][0] + buf * TILEB;
        #pragma unroll
        for (int fg = 0; fg < 2; ++fg) {
            const int c = fg * 16 + l15;
            const char* rowp = bufc + c * 512;
            const int cx = c & 7;
            bf16x8 bf[8];
            #pragma unroll
            for (int ks = 0; ks < 8; ++ks)
                bf[ks] = *(const bf16x8*)(rowp + (((ks * 4 + lq) ^ cx) << 4));

            f32x4 acc[4] = {{0.f,0.f,0.f,0.f},{0.f,0.f,0.f,0.f},
                            {0.f,0.f,0.f,0.f},{0.f,0.f,0.f,0.f}};
            __builtin_amdgcn_s_setprio(1);
            #pragma unroll
            for (int ks = 0; ks < 8; ++ks)
                #pragma unroll
                for (int g = 0; g < 4; ++g)
                    acc[g] = __builtin_amdgcn_mfma_f32_16x16x32_bf16(afr[g][ks], bf[ks], acc[g], 0, 0, 0);
            __builtin_amdgcn_s_setprio(0);

            #pragma unroll
            for (int g = 0; g < 4; ++g)
                #pragma unroll
                for (int r = 0; r < 4; ++r)
                    S[g][r] += exp2f(fmaf(acc[g][r], 2.8853900817779268f, -2.8853900817779268f));
        }
    };

    stage(0, 0); stage(1, 1); stage(2, 2);   // 12 loads in flight per wave

    int sb = PD;   // next stage buffer
    int cb = 0;    // current compute buffer
    #pragma unroll 1
    for (int t = 0; t < NT - PD; ++t) {
        stage(sb, t + PD);
        WAITVM(12);                          // my tile-t loads retired (FIFO)
        __builtin_amdgcn_s_barrier();        // all waves' tile-t loads retired
        compute(cb);
        sb = (sb == RING - 1) ? 0 : sb + 1;
        cb = (cb == RING - 1) ? 0 : cb + 1;
    }
    WAITVM(8);  __builtin_amdgcn_s_barrier(); compute(cb); cb = (cb == RING - 1) ? 0 : cb + 1;
    WAITVM(4);  __builtin_amdgcn_s_barrier(); compute(cb); cb = (cb == RING - 1) ? 0 : cb + 1;
    WAITVM(0);  __builtin_amdgcn_s_barrier(); compute(cb);

    // reduce across the 16 column-lanes
    #pragma unroll
    for (int off = 1; off < 16; off <<= 1)
        #pragma unroll
        for (int g = 0; g < 4; ++g)
            #pragma unroll
            for (int r = 0; r < 4; ++r) S[g][r] += __shfl_xor(S[g][r], off);

    if (l15 == 0) {
        #pragma unroll
        for (int g = 0; g < 4; ++g)
            #pragma unroll
            for (int r = 0; r < 4; ++r) {
                int row = r0 + wave * 64 + g * 16 + lq * 4 + r;
                float v = S[g][r];
                // diagonal col lies in this slice: its exp(2*||r||^2-2) ~= 1.0
                if (row >= c0 && row < c0 + CPB) v -= 1.0f;
                partial[(size_t)cs * N2 + row] = v;
            }
    }
}

// ---------------- Kernel 3a: per-row log of summed partials, per-block sums ----------------
__global__ __launch_bounds__(256) void finish1_kernel(const float* __restrict__ partial,
                                                      float* __restrict__ blocksum) {
    int row = blockIdx.x * 256 + threadIdx.x;
    float s = 0.f;
    #pragma unroll
    for (int cs = 0; cs < CSPLIT; ++cs) s += partial[(size_t)cs * N2 + row];
    float v = logf(s);
    #pragma unroll
    for (int off = 32; off; off >>= 1) v += __shfl_xor(v, off);
    __shared__ float ws4[4];
    if ((threadIdx.x & 63) == 0) ws4[threadIdx.x >> 6] = v;
    __syncthreads();
    if (threadIdx.x == 0) blocksum[blockIdx.x] = ws4[0] + ws4[1] + ws4[2] + ws4[3];
}

// ---------------- Kernel 3b: final scalar ----------------
__global__ __launch_bounds__(256) void finish2_kernel(const float* __restrict__ blocksum,
                                                      const float* __restrict__ pos,
                                                      float* __restrict__ out) {
    float v = (threadIdx.x < 32) ? blocksum[threadIdx.x] : 0.f;
    float p = 0.f;
    for (int i = threadIdx.x; i < BDIM; i += 256) p += pos[i];
    float t = v - 4.0f * p;
    #pragma unroll
    for (int off = 32; off; off >>= 1) t += __shfl_xor(t, off);
    __shared__ float ws4[4];
    if ((threadIdx.x & 63) == 0) ws4[threadIdx.x >> 6] = t;
    __syncthreads();
    if (threadIdx.x == 0)
        out[0] = 2.0f + (ws4[0] + ws4[1] + ws4[2] + ws4[3]) / (float)N2;
}

extern "C" void kernel_launch(void* const* d_in, const int* in_sizes, int n_in,
                              void* d_out, int out_size, void* d_ws, size_t ws_size,
                              hipStream_t stream) {
    const float* z1 = (const float*)d_in[0];
    const float* z2 = (const float*)d_in[1];
    float* out = (float*)d_out;

    __bf16* reps     = (__bf16*)d_ws;                                  // 4 MB
    float*  partial  = (float*)((char*)d_ws + (size_t)N2 * DDIM * 2);  // 512 KB
    float*  pos      = partial + (size_t)CSPLIT * N2;                  // 16 KB
    float*  blocksum = pos + BDIM;                                     // 128 B

    norm_kernel<<<BDIM / 4, 256, 0, stream>>>(z1, z2, reps, pos);
    lse4_kernel<<<(N2 / BROWS) * CSPLIT, 256, 0, stream>>>(reps, partial);
    finish1_kernel<<<N2 / 256, 256, 0, stream>>>(partial, blocksum);
    finish2_kernel<<<1, 256, 0, stream>>>(blocksum, pos, out);
}